// Round 3
// baseline (49.151 us; speedup 1.0000x reference)
//
#include <hip/hip_runtime.h>
#include <hip/hip_bf16.h>
#include <math.h>

#define N_    1536
#define HID_  64
#define DX_   192
#define JW_   12
#define JCH_  (N_ / JW_)   /* 128 j-chunks */
#define IB_   (N_ / 64)    /* 24 i-blocks of 64 rows */

typedef float v2f __attribute__((ext_vector_type(2)));

// ---------------------------------------------------------------------------
// Kernel 1: AmT[h][i] = sum_k y[i,k]*W1[h,192+k] + b1[h]   (TRANSPOSED, h-major)
//           Bm[j][h]  = sum_k x[j,k]*W1[h,k]               (row-major)
// 192 blocks x 256 thr. bid<96: A-side (y, W1 second half). else B-side (x).
// W1-half staged TRANSPOSED in LDS as float4[48][64] (lane=h -> conflict-free).
// ---------------------------------------------------------------------------
__global__ __launch_bounds__(256) void k1(
    const float* __restrict__ x, const float* __restrict__ y,
    const float* __restrict__ W1, const float* __restrict__ b1,
    float* __restrict__ AmT, float* __restrict__ Bm)
{
    __shared__ float4 w1t[48 * 64];   // 48 KiB
    int t = threadIdx.x;
    int h = t & 63;
    int w = t >> 6;                   // wave id 0..3
    bool aSide = (blockIdx.x < 96);

    const float4* w1row = (const float4*)(W1 + h * (2 * DX_) + (aSide ? DX_ : 0));
    int kq0 = w * 12;
    #pragma unroll
    for (int q = 0; q < 12; ++q)
        w1t[(kq0 + q) * 64 + h] = w1row[kq0 + q];
    __syncthreads();

    int row0 = (blockIdx.x % 96) * 16;
    const float* inp = aSide ? y : x;
    float b1h = aSide ? b1[h] : 0.f;

    #pragma unroll
    for (int p = 0; p < 4; ++p) {
        int row = row0 + p * 4 + w;
        const float4* in4 = (const float4*)(inp + row * DX_);
        float acc = b1h;
        #pragma unroll
        for (int q = 0; q < 48; ++q) {
            float4 wv = w1t[q * 64 + h];
            float4 iv = in4[q];
            acc = fmaf(iv.x, wv.x, acc);
            acc = fmaf(iv.y, wv.y, acc);
            acc = fmaf(iv.z, wv.z, acc);
            acc = fmaf(iv.w, wv.w, acc);
        }
        if (aSide) AmT[h * N_ + row] = acc;   // transposed store
        else       Bm[row * HID_ + h] = acc;  // row-major
    }
}

// ---------------------------------------------------------------------------
// Kernel 2: z[i,j] = sum_h W2[h]*relu(A[i,h] + B[j,h]) + b2
//   part[jc][i] = sum_{j in chunk} exp(z)      (exp(softplus(z)) = 1 + e^z)
//   t0[i] = softplus(z[i,i]) on the diagonal.
// 768 blocks x 256 thr = 3072 waves = exactly 3 waves/SIMD chip-wide.
// lane <-> i; j wave-uniform (W2/B-row via scalar path); packed v_pk_* fp32:
// 3 VOP3P per 2 h-positions (pk_add, pk_max, pk_fma).
// ---------------------------------------------------------------------------
__global__ __launch_bounds__(256) void k2(
    const float* __restrict__ AmT, const float* __restrict__ Bm,
    const float* __restrict__ W2, const float* __restrict__ b2,
    float* __restrict__ part, float* __restrict__ t0)
{
    int lane = threadIdx.x & 63;
    int sub  = threadIdx.x >> 6;
    int jc   = blockIdx.x % JCH_;
    int ib   = (blockIdx.x / JCH_) * 4 + sub;
    int i    = ib * 64 + lane;

    // coalesced prologue: a[h] for this lane's i, h-major global layout
    v2f a2[HID_ / 2];
    #pragma unroll
    for (int h2 = 0; h2 < HID_ / 2; ++h2) {
        a2[h2].x = AmT[(2 * h2 + 0) * N_ + i];
        a2[h2].y = AmT[(2 * h2 + 1) * N_ + i];
    }

    const v2f* Wr = (const v2f*)W2;   // uniform -> scalar regs
    float b2v = b2[0];
    float se = 0.f;

    for (int jj = 0; jj < JW_; ++jj) {
        int j = jc * JW_ + jj;
        const v2f* Br = (const v2f*)(Bm + j * HID_);   // uniform row
        v2f acc0 = {0.f, 0.f}, acc1 = {0.f, 0.f};
        #pragma unroll
        for (int q = 0; q < HID_ / 2; q += 2) {
            v2f s0 = a2[q]     + Br[q];
            v2f s1 = a2[q + 1] + Br[q + 1];
            v2f r0 = __builtin_elementwise_max(s0, (v2f){0.f, 0.f});
            v2f r1 = __builtin_elementwise_max(s1, (v2f){0.f, 0.f});
            acc0 = __builtin_elementwise_fma(Wr[q],     r0, acc0);
            acc1 = __builtin_elementwise_fma(Wr[q + 1], r1, acc1);
        }
        float p = (acc0.x + acc0.y) + (acc1.x + acc1.y) + b2v;
        se += __expf(p);
        if (j == i) {
            t0[i] = fmaxf(p, 0.f) + log1pf(__expf(-fabsf(p)));
        }
    }
    part[jc * N_ + i] = se;
}

// ---------------------------------------------------------------------------
// Kernel 3a: per 64-row block: partial sum of (log(N + sum_jc part) - t0[i]), f64.
// Kernel 3b: combine 24 partials -> out = sum/N - log N.
// ---------------------------------------------------------------------------
__global__ __launch_bounds__(64) void k3a(
    const float* __restrict__ part, const float* __restrict__ t0,
    double* __restrict__ red)
{
    int i = blockIdx.x * 64 + threadIdx.x;
    double s = (double)N_;   // the "+1" per j from exp(softplus(z)) = 1 + e^z
    for (int jc = 0; jc < JCH_; ++jc) s += (double)part[jc * N_ + i];
    double v = log(s) - (double)t0[i];
    #pragma unroll
    for (int m = 32; m; m >>= 1) v += __shfl_xor(v, m, 64);
    if (threadIdx.x == 0) red[blockIdx.x] = v;
}

__global__ __launch_bounds__(64) void k3b(
    const double* __restrict__ red, float* __restrict__ out)
{
    double v = (threadIdx.x < IB_) ? red[threadIdx.x] : 0.0;
    #pragma unroll
    for (int m = 32; m; m >>= 1) v += __shfl_xor(v, m, 64);
    if (threadIdx.x == 0)
        out[0] = (float)(v / (double)N_ - log((double)N_));
}

extern "C" void kernel_launch(void* const* d_in, const int* in_sizes, int n_in,
                              void* d_out, int out_size, void* d_ws, size_t ws_size,
                              hipStream_t stream)
{
    const float* x  = (const float*)d_in[0];
    const float* y  = (const float*)d_in[1];
    const float* W1 = (const float*)d_in[2];
    const float* b1 = (const float*)d_in[3];
    const float* W2 = (const float*)d_in[4];
    const float* b2 = (const float*)d_in[5];
    // d_in[6] = mask: all-ones, unused by the reference math.

    double* red  = (double*)d_ws;          // 24 doubles (first, for alignment)
    float*  ws   = (float*)d_ws + 64;      // floats after 256 B
    float*  AmT  = ws;                     // HID*N   (h-major)
    float*  Bm   = AmT + HID_ * N_;        // N*HID   (row-major)
    float*  part = Bm + N_ * HID_;         // JCH_*N
    float*  t0   = part + JCH_ * N_;       // N

    hipLaunchKernelGGL(k1, dim3(192), dim3(256), 0, stream,
                       x, y, W1, b1, AmT, Bm);
    hipLaunchKernelGGL(k2, dim3((IB_ / 4) * JCH_), dim3(256), 0, stream,
                       AmT, Bm, W2, b2, part, t0);
    hipLaunchKernelGGL(k3a, dim3(IB_), dim3(64), 0, stream, part, t0, red);
    hipLaunchKernelGGL(k3b, dim3(1), dim3(64), 0, stream, red, (float*)d_out);
}

// Round 4
// 41.799 us; speedup vs baseline: 1.1759x; 1.1759x over previous
//
#include <hip/hip_runtime.h>
#include <hip/hip_bf16.h>
#include <math.h>

#define N_    1536
#define HID_  64
#define DX_   192
#define JW_   12
#define JCH_  (N_ / JW_)   /* 128 j-chunks */
#define IB_   (N_ / 64)    /* 24 i-blocks of 64 rows */

// ---------------------------------------------------------------------------
// Kernel 1: AmT[h][i] = sum_k y[i,k]*W1[h,192+k] + b1[h]   (h-major)
//           Bm[j][h]  = sum_k x[j,k]*W1[h,k]               (row-major)
//           cv[i] = sum_h (W2[h]/2)*A[i,h] + b2 ; dv[j] = sum_h (W2[h]/2)*B[j,h]
// 192 blocks x 256 thr. bid<96: A-side (y, W1 second half). else B-side (x).
// W1-half staged transposed in LDS as float4[48][64] (lane=h, conflict-free).
// ---------------------------------------------------------------------------
__global__ __launch_bounds__(256) void k1(
    const float* __restrict__ x, const float* __restrict__ y,
    const float* __restrict__ W1, const float* __restrict__ b1,
    const float* __restrict__ W2, const float* __restrict__ b2,
    float* __restrict__ AmT, float* __restrict__ Bm,
    float* __restrict__ cv, float* __restrict__ dv)
{
    __shared__ float4 w1t[48 * 64];   // 48 KiB
    int t = threadIdx.x;
    int h = t & 63;
    int w = t >> 6;                   // wave id 0..3
    bool aSide = (blockIdx.x < 96);

    const float4* w1row = (const float4*)(W1 + h * (2 * DX_) + (aSide ? DX_ : 0));
    int kq0 = w * 12;
    #pragma unroll
    for (int q = 0; q < 12; ++q)
        w1t[(kq0 + q) * 64 + h] = w1row[kq0 + q];
    __syncthreads();

    int row0 = (blockIdx.x % 96) * 16;
    const float* inp = aSide ? y : x;
    float b1h = aSide ? b1[h] : 0.f;
    float wph = 0.5f * W2[h];
    float b2v = b2[0];

    #pragma unroll
    for (int p = 0; p < 4; ++p) {
        int row = row0 + p * 4 + w;
        const float4* in4 = (const float4*)(inp + row * DX_);
        float acc = b1h;
        #pragma unroll
        for (int q = 0; q < 48; ++q) {
            float4 wv = w1t[q * 64 + h];
            float4 iv = in4[q];
            acc = fmaf(iv.x, wv.x, acc);
            acc = fmaf(iv.y, wv.y, acc);
            acc = fmaf(iv.z, wv.z, acc);
            acc = fmaf(iv.w, wv.w, acc);
        }
        if (aSide) AmT[h * N_ + row] = acc;    // h-major
        else       Bm[row * HID_ + h] = acc;   // row-major

        float v = wph * acc;
        #pragma unroll
        for (int m = 32; m; m >>= 1) v += __shfl_xor(v, m, 64);
        if (h == 0) {
            if (aSide) cv[row] = v + b2v;
            else       dv[row] = v;
        }
    }
}

// ---------------------------------------------------------------------------
// Kernel 2: z[i,j] = cv_i + dv_j + sum_h (W2[h]/2)*|A[i,h] + B[j,h]|
//   (identical to sum_h W2[h]*relu(A+B)+b2 via relu(v) = (v+|v|)/2)
//   part[jc][i] = sum_{j in chunk} exp(z)      (exp(softplus(z)) = 1 + e^z)
//   t0[i] = softplus(z[i,i]) on the diagonal.
// 768 blocks x 256 thr = 3072 waves = exactly 3.0 waves/SIMD (no tail).
// lane <-> i; j wave-uniform (W2/B-row via scalar path); inner loop is
// v_add_f32 + v_fma_f32(abs modifier) = 2 VALU cycles per h-position;
// 4 independent accumulator chains for ILP.
// ---------------------------------------------------------------------------
__global__ __launch_bounds__(256) void k2(
    const float* __restrict__ AmT, const float* __restrict__ Bm,
    const float* __restrict__ W2, const float* __restrict__ cv,
    const float* __restrict__ dv,
    float* __restrict__ part, float* __restrict__ t0)
{
    int lane = threadIdx.x & 63;
    int sub  = threadIdx.x >> 6;
    int jc   = blockIdx.x % JCH_;
    int ib   = (blockIdx.x / JCH_) * 4 + sub;
    int i    = ib * 64 + lane;

    // coalesced prologue: a[h] for this lane's i (h-major layout)
    float a[HID_];
    #pragma unroll
    for (int h = 0; h < HID_; ++h) a[h] = AmT[h * N_ + i];

    // uniform weights -> scalar loads / SGPRs
    float w[HID_];
    #pragma unroll
    for (int h = 0; h < HID_; ++h) w[h] = 0.5f * W2[h];

    float ci = cv[i];
    float se = 0.f;

    for (int jj = 0; jj < JW_; ++jj) {
        int j = jc * JW_ + jj;
        const float4* Br = (const float4*)(Bm + j * HID_);   // uniform row
        float p0 = ci + dv[j];
        float p1 = 0.f, p2 = 0.f, p3 = 0.f;
        #pragma unroll
        for (int q = 0; q < HID_ / 4; ++q) {
            float4 tv = Br[q];
            p0 = fmaf(w[4*q+0], fabsf(a[4*q+0] + tv.x), p0);
            p1 = fmaf(w[4*q+1], fabsf(a[4*q+1] + tv.y), p1);
            p2 = fmaf(w[4*q+2], fabsf(a[4*q+2] + tv.z), p2);
            p3 = fmaf(w[4*q+3], fabsf(a[4*q+3] + tv.w), p3);
        }
        float p = (p0 + p1) + (p2 + p3);
        se += __expf(p);
        if (j == i) {
            t0[i] = fmaxf(p, 0.f) + log1pf(__expf(-fabsf(p)));
        }
    }
    part[jc * N_ + i] = se;
}

// ---------------------------------------------------------------------------
// Kernel 3a: per 64-row block: partial sum of (log(N + sum_jc part) - t0[i]), f64.
// Kernel 3b: combine 24 partials -> out = sum/N - log N.
// ---------------------------------------------------------------------------
__global__ __launch_bounds__(64) void k3a(
    const float* __restrict__ part, const float* __restrict__ t0,
    double* __restrict__ red)
{
    int i = blockIdx.x * 64 + threadIdx.x;
    double s = (double)N_;   // the "+1" per j from exp(softplus(z)) = 1 + e^z
    #pragma unroll 8
    for (int jc = 0; jc < JCH_; ++jc) s += (double)part[jc * N_ + i];
    double v = log(s) - (double)t0[i];
    #pragma unroll
    for (int m = 32; m; m >>= 1) v += __shfl_xor(v, m, 64);
    if (threadIdx.x == 0) red[blockIdx.x] = v;
}

__global__ __launch_bounds__(64) void k3b(
    const double* __restrict__ red, float* __restrict__ out)
{
    double v = (threadIdx.x < IB_) ? red[threadIdx.x] : 0.0;
    #pragma unroll
    for (int m = 32; m; m >>= 1) v += __shfl_xor(v, m, 64);
    if (threadIdx.x == 0)
        out[0] = (float)(v / (double)N_ - log((double)N_));
}

extern "C" void kernel_launch(void* const* d_in, const int* in_sizes, int n_in,
                              void* d_out, int out_size, void* d_ws, size_t ws_size,
                              hipStream_t stream)
{
    const float* x  = (const float*)d_in[0];
    const float* y  = (const float*)d_in[1];
    const float* W1 = (const float*)d_in[2];
    const float* b1 = (const float*)d_in[3];
    const float* W2 = (const float*)d_in[4];
    const float* b2 = (const float*)d_in[5];
    // d_in[6] = mask: all-ones, unused by the reference math.

    double* red  = (double*)d_ws;          // 24 doubles (first, for alignment)
    float*  ws   = (float*)d_ws + 64;      // floats after 256 B
    float*  AmT  = ws;                     // HID*N   (h-major)
    float*  Bm   = AmT + HID_ * N_;        // N*HID   (row-major)
    float*  cv   = Bm + N_ * HID_;         // N
    float*  dv   = cv + N_;                // N
    float*  part = dv + N_;                // JCH_*N
    float*  t0   = part + JCH_ * N_;       // N

    hipLaunchKernelGGL(k1, dim3(192), dim3(256), 0, stream,
                       x, y, W1, b1, W2, b2, AmT, Bm, cv, dv);
    hipLaunchKernelGGL(k2, dim3((IB_ / 4) * JCH_), dim3(256), 0, stream,
                       AmT, Bm, W2, cv, dv, part, t0);
    hipLaunchKernelGGL(k3a, dim3(IB_), dim3(64), 0, stream, part, t0, red);
    hipLaunchKernelGGL(k3b, dim3(1), dim3(64), 0, stream, red, (float*)d_out);
}